// Round 10
// baseline (78.462 us; speedup 1.0000x reference)
//
#include <hip/hip_runtime.h>
#include <stdint.h>

#define AS_G __attribute__((address_space(1)))
#define AS_L __attribute__((address_space(3)))

typedef __bf16 bf16x8 __attribute__((ext_vector_type(8)));
typedef float  f32x4  __attribute__((ext_vector_type(4)));

static constexpr int NIMG = 16, CIN = 128, H = 64, W = 64, OCH = 128;
static constexpr int HO = 62, WO = 62;
static constexpr int PIX = HO * WO;            // 3844
static constexpr int M_TOT = NIMG * PIX;       // 61504
static constexpr int K_TOT = CIN * 9;          // 1152
static constexpr int MBLK = 512;               // block m-extent (4 waves x 128)
static constexpr int NMB = (M_TOT + MBLK - 1) / MBLK;   // 121
static constexpr int NWG = NMB * 2;            // x2 o-halves = 242 blocks
static constexpr int LDS_BYTES = 64 * K_TOT * 2;        // 144 KB weight image

__device__ __forceinline__ unsigned short f2bf(float f) {
    union { float f; uint32_t u; } v; v.f = f;
    uint32_t u = v.u;
    return (unsigned short)((u + 0x7FFFu + ((u >> 16) & 1u)) >> 16);
}

// Fused prep: blocks [0,1024): NCHW fp32 -> NHWC bf16; rest: weight prep.
__global__ __launch_bounds__(256) void prep_kernel(const float* __restrict__ x,
                                                   const float* __restrict__ wsrc,
                                                   unsigned short* __restrict__ xt,
                                                   unsigned short* __restrict__ bpd) {
    __shared__ float lds[CIN][W + 4];
    if (blockIdx.x < NIMG * H) {
        const int n   = blockIdx.x >> 6;
        const int h   = blockIdx.x & 63;
        const int tid = threadIdx.x;
        {
            const int c  = tid >> 1;
            const int w0 = (tid & 1) * 32;
            const float* src = x + (((size_t)(n * CIN + c) * H + h) * W + w0);
            #pragma unroll
            for (int j = 0; j < 8; ++j) {
                float4 v = *reinterpret_cast<const float4*>(src + j * 4);
                *reinterpret_cast<float4*>(&lds[c][w0 + j * 4]) = v;
            }
        }
        __syncthreads();
        {
            const int w  = tid >> 2;
            const int c0 = (tid & 3) * 32;
            unsigned short* dst = xt + (((size_t)(n * H + h) * W + w) * CIN + c0);
            uint32_t pk[16];
            #pragma unroll
            for (int j = 0; j < 16; ++j) {
                uint32_t lo = f2bf(lds[c0 + 2 * j][w]);
                uint32_t hi = f2bf(lds[c0 + 2 * j + 1][w]);
                pk[j] = lo | (hi << 16);
            }
            #pragma unroll
            for (int j = 0; j < 4; ++j) {
                *reinterpret_cast<uint4*>(dst + j * 8) =
                    make_uint4(pk[4 * j], pk[4 * j + 1], pk[4 * j + 2], pk[4 * j + 3]);
            }
        }
    } else {
        int tid = (blockIdx.x - NIMG * H) * 256 + threadIdx.x;
        if (tid < OCH * K_TOT) {
            int o  = tid / K_TOT;
            int kp = tid - o * K_TOT;   // kp = t*128 + c
            int t  = kp >> 7;
            int c  = kp & 127;
            bpd[tid] = f2bf(wsrc[o * K_TOT + c * 9 + t]);
        }
    }
}

// Barrier-free implicit-GEMM conv.
// Block: 256 thr (4 waves), one 64-o half of weights RESIDENT in LDS (144 KB,
// staged once, ONE barrier). Each wave owns 128 m x 64 o. Main loop over 9
// taps: 16 bfr ds_reads + 32 af global_load_dwordx4 (NHWC: per-lane-contiguous
// 16 B, L2-served) + 128 MFMA. NO per-step barriers, waves free-run.
// mfma(bfr, af, acc): D rows = o, D cols = m -> coalesced stores.
__global__ __launch_bounds__(256, 1) void gemm_kernel(const unsigned short* __restrict__ xt,
                                                      const unsigned short* __restrict__ bp,
                                                      const float* __restrict__ bias,
                                                      float* __restrict__ out) {
    extern __shared__ char lds[];
    const int tid  = threadIdx.x;
    const int wv   = tid >> 6;
    const int lane = tid & 63;
    const int lr   = lane & 15, lq = lane >> 4;

    // ---- bijective XCD swizzle (242 = 8*30+2: q=30, r=2) ----
    const int orig = blockIdx.x;
    const int xcd  = orig & 7;
    const int idx  = orig >> 3;
    const int wg   = (xcd < 2 ? xcd * 31 : 62 + (xcd - 2) * 30) + idx;
    const int mblk = wg >> 1;            // 0..120
    const int oh   = wg & 1;             // o-half: [oh*64, oh*64+64)

    // ---- one-shot weight staging: 64 o x 1152 k' bf16, rows 2304 B.
    // Logical col-byte L stored at phys L ^ ((o&7)<<4); linear LDS dest
    // (wave-uniform base + lane*16) + pre-swizzled per-lane global source ----
    {
        const unsigned short* wbase = bp + oh * 64 * K_TOT;
        #pragma unroll
        for (int p = 0; p < 36; ++p) {
            int s  = p * 256 + tid;              // 16B slot, 9216 total
            int o  = s / 144;                    // 144 slots per o-row
            int q  = s - o * 144;
            int Lx = (q * 16) ^ ((o & 7) << 4);  // pre-swizzled source col-byte
            __builtin_amdgcn_global_load_lds(
                (AS_G unsigned int*)(wbase + o * K_TOT + (Lx >> 1)),
                (AS_L unsigned int*)(lds + p * 4096 + wv * 1024),   // uniform base
                16, 0, 0);
        }
    }

    // ---- per-wave m geometry (wave owns 128 m) ----
    int pixBase[8], obase[8];
    bool valid[8];
    #pragma unroll
    for (int mi = 0; mi < 8; ++mi) {
        int m = mblk * MBLK + wv * 128 + mi * 16 + lr;
        valid[mi] = (m < M_TOT);
        if (m >= M_TOT) m = M_TOT - 1;
        int n  = m / PIX;
        int r  = m - n * PIX;
        int y  = r / WO;
        int xx = r - y * WO;
        pixBase[mi] = ((n * H + y) * W + xx) * CIN;     // NHWC elems, tap(0,0)
        obase[mi]   = n * OCH * PIX + y * WO + xx;      // out elems, o=0
    }

    // bfr LDS read offsets within a tap: o-row = ni*16+lr (o&7 == lr&7),
    // within-tap col-byte = ks*64 + lq*16 (tap adds t*256, untouched by swz)
    int bOff[4][4];
    #pragma unroll
    for (int ks = 0; ks < 4; ++ks)
        #pragma unroll
        for (int ni = 0; ni < 4; ++ni)
            bOff[ks][ni] = (ni * 16 + lr) * 2304 +
                           ((ks * 64 + lq * 16) ^ ((lr & 7) << 4));

    f32x4 acc[8][4];
    #pragma unroll
    for (int a = 0; a < 8; ++a)
        #pragma unroll
        for (int b = 0; b < 4; ++b)
            acc[a][b] = (f32x4){0.f, 0.f, 0.f, 0.f};

    // wait for weight image, once
    asm volatile("s_waitcnt vmcnt(0)" ::: "memory");
    __builtin_amdgcn_s_barrier();

    // ---- main loop: 9 taps, NO barriers ----
    for (int t = 0; t < 9; ++t) {
        const int kh = t / 3, kw = t - kh * 3;
        const int tapoff = (kh * W + kw) * CIN;          // elems
        const int kfrag  = lq * 8;                       // within-32k lane chunk
        const int tlds   = t * 256;                      // tap byte offset in row

        bf16x8 bfr[4][4];
        #pragma unroll
        for (int ks = 0; ks < 4; ++ks)
            #pragma unroll
            for (int ni = 0; ni < 4; ++ni)
                bfr[ks][ni] = *(const bf16x8*)(lds + tlds + bOff[ks][ni]);

        bf16x8 af[8][4];
        #pragma unroll
        for (int mi = 0; mi < 8; ++mi) {
            const unsigned short* ap = xt + pixBase[mi] + tapoff + kfrag;
            #pragma unroll
            for (int ks = 0; ks < 4; ++ks)
                af[mi][ks] = *(const bf16x8*)(ap + ks * 32);
        }

        #pragma unroll
        for (int mi = 0; mi < 8; ++mi)
            #pragma unroll
            for (int ks = 0; ks < 4; ++ks)
                #pragma unroll
                for (int ni = 0; ni < 4; ++ni)
                    acc[mi][ni] = __builtin_amdgcn_mfma_f32_16x16x32_bf16(
                        bfr[ks][ni], af[mi][ks], acc[mi][ni], 0, 0, 0);
    }

    // ---- epilogue: D col = lane&15 = m (consecutive x), row = lq*4+j = o ----
    f32x4 bv[4];
    #pragma unroll
    for (int ni = 0; ni < 4; ++ni)
        bv[ni] = *(const f32x4*)(bias + oh * 64 + ni * 16 + lq * 4);
    #pragma unroll
    for (int mi = 0; mi < 8; ++mi) {
        if (valid[mi]) {
            float* ob = out + obase[mi];
            #pragma unroll
            for (int ni = 0; ni < 4; ++ni) {
                const int o = oh * 64 + ni * 16 + lq * 4;
                #pragma unroll
                for (int j = 0; j < 4; ++j)
                    ob[(size_t)(o + j) * PIX] = acc[mi][ni][j] + bv[ni][j];
            }
        }
    }
}

extern "C" void kernel_launch(void* const* d_in, const int* in_sizes, int n_in,
                              void* d_out, int out_size, void* d_ws, size_t ws_size,
                              hipStream_t stream) {
    const float* x    = (const float*)d_in[0];
    const float* wsrc = (const float*)d_in[1];
    const float* bias = (const float*)d_in[2];
    float* out = (float*)d_out;
    unsigned short* xt = (unsigned short*)d_ws;                 // 16 MiB NHWC bf16
    unsigned short* bp = xt + (size_t)NIMG * H * W * CIN;       // 288 KiB weights
    prep_kernel<<<dim3(NIMG * H + (OCH * K_TOT + 255) / 256), dim3(256), 0, stream>>>(
        x, wsrc, xt, bp);
    gemm_kernel<<<dim3(NWG), dim3(256), LDS_BYTES, stream>>>(xt, bp, bias, out);
}

// Round 11
// 48.957 us; speedup vs baseline: 1.6027x; 1.6027x over previous
//
#include <hip/hip_runtime.h>
#include <stdint.h>

#define AS_G __attribute__((address_space(1)))
#define AS_L __attribute__((address_space(3)))

typedef __bf16 bf16x8 __attribute__((ext_vector_type(8)));
typedef float  f32x4  __attribute__((ext_vector_type(4)));

static constexpr int NIMG = 16, CIN = 128, H = 64, W = 64, OCH = 128;
static constexpr int HO = 62, WO = 62;
static constexpr int PIX = HO * WO;            // 3844
static constexpr int M_TOT = NIMG * PIX;       // 61504
static constexpr int K_TOT = CIN * 9;          // 1152
static constexpr int BM = 128, BK = 64;
static constexpr int KSTEPS = K_TOT / BK;      // 18
static constexpr int NWG = (M_TOT + BM - 1) / BM;   // 481

__device__ __forceinline__ unsigned short f2bf(float f) {
    union { float f; uint32_t u; } v; v.f = f;
    uint32_t u = v.u;
    return (unsigned short)((u + 0x7FFFu + ((u >> 16) & 1u)) >> 16);
}

// Fused prep: blocks [0,1024): NCHW fp32 -> NHWC bf16; rest: weight prep.
__global__ __launch_bounds__(256) void prep_kernel(const float* __restrict__ x,
                                                   const float* __restrict__ wsrc,
                                                   unsigned short* __restrict__ xt,
                                                   unsigned short* __restrict__ bpd) {
    __shared__ float lds[CIN][W + 4];
    if (blockIdx.x < NIMG * H) {
        const int n   = blockIdx.x >> 6;
        const int h   = blockIdx.x & 63;
        const int tid = threadIdx.x;
        {
            const int c  = tid >> 1;
            const int w0 = (tid & 1) * 32;
            const float* src = x + (((size_t)(n * CIN + c) * H + h) * W + w0);
            #pragma unroll
            for (int j = 0; j < 8; ++j) {
                float4 v = *reinterpret_cast<const float4*>(src + j * 4);
                *reinterpret_cast<float4*>(&lds[c][w0 + j * 4]) = v;
            }
        }
        __syncthreads();
        {
            const int w  = tid >> 2;
            const int c0 = (tid & 3) * 32;
            unsigned short* dst = xt + (((size_t)(n * H + h) * W + w) * CIN + c0);
            uint32_t pk[16];
            #pragma unroll
            for (int j = 0; j < 16; ++j) {
                uint32_t lo = f2bf(lds[c0 + 2 * j][w]);
                uint32_t hi = f2bf(lds[c0 + 2 * j + 1][w]);
                pk[j] = lo | (hi << 16);
            }
            #pragma unroll
            for (int j = 0; j < 4; ++j) {
                *reinterpret_cast<uint4*>(dst + j * 8) =
                    make_uint4(pk[4 * j], pk[4 * j + 1], pk[4 * j + 2], pk[4 * j + 3]);
            }
        }
    } else {
        int tid = (blockIdx.x - NIMG * H) * 256 + threadIdx.x;
        if (tid < OCH * K_TOT) {
            int o  = tid / K_TOT;
            int kp = tid - o * K_TOT;   // kp = t*128 + c
            int t  = kp >> 7;
            int c  = kp & 127;
            bpd[tid] = f2bf(wsrc[o * K_TOT + c * 9 + t]);
        }
    }
}

// Implicit-GEMM conv: C[m][o] = sum_k A[m][k]*W[o][k], m=(n,y,x), k=(t,c)
// m97-exact geometry: BM=BN=128, BK=64, 4 waves each owning 64m x 64o
// (acc 4x4), single-buffer 2-barrier K-loop, gl_lds width-16 staging with
// 0-conflict XOR swizzle, bijective XCD swizzle, swapped-operand MFMA for
// coalesced stores (D rows = o, D cols = m).
__global__ __launch_bounds__(256) void gemm_kernel(const unsigned short* __restrict__ xt,
                                                   const unsigned short* __restrict__ bp,
                                                   const float* __restrict__ bias,
                                                   float* __restrict__ out) {
    __shared__ alignas(16) unsigned short As[BM * BK];   // 16 KB, XOR-swizzled
    __shared__ alignas(16) unsigned short Bs[OCH * BK];  // 16 KB, XOR-swizzled
    const int tid  = threadIdx.x;
    const int wv   = tid >> 6;
    const int lane = tid & 63;

    // ---- bijective XCD swizzle (481 = 8*60+1: q=60, r=1) ----
    const int orig = blockIdx.x;
    const int xcd  = orig & 7;
    const int idx  = orig >> 3;
    const int wg   = (xcd == 0 ? 0 : 61 + (xcd - 1) * 60) + idx;
    const int m0   = wg * BM;

    // staging: slot s covers bytes [s*16,s*16+16); row = s>>3 (8 slots / 128B row)
    // phys_byte = row*128 + (colbyte ^ ((row&7)<<4)); row&7 == lane>>3:
    const int csel = ((lane & 7) ^ (lane >> 3)) * 8;   // source col offset, elems
    int aBase[4], bBase[4];
    #pragma unroll
    for (int i = 0; i < 4; ++i) {
        int row = (wv * 4 + i) * 8 + (lane >> 3);      // m-row 0..127
        int m = m0 + row; if (m >= M_TOT) m = M_TOT - 1;   // clamp; store-masked
        int n  = m / PIX;
        int r  = m - n * PIX;
        int y  = r / WO;
        int xx = r - y * WO;
        aBase[i] = ((n * H + y) * W + xx) * CIN;       // NHWC elem index, tap 0
        bBase[i] = ((wv * 4 + i) * 8 + (lane >> 3)) * K_TOT;   // o-row 0..127
    }

    // compute-side fragment addresses: wave tile 64m x 64o (2x2 wave grid)
    const int wr = wv >> 1, wc = wv & 1;
    const int lr = lane & 15, lq = lane >> 4;
    const int aRow = (wr * 64 + lr) * 128;             // byte offset of m-row
    const int bRow = (wc * 64 + lr) * 128;             // byte offset of o-row
    int colx[2];
    #pragma unroll
    for (int ks = 0; ks < 2; ++ks)
        colx[ks] = (ks * 64 + lq * 16) ^ ((lane & 7) << 4);

    f32x4 acc[4][4];
    #pragma unroll
    for (int a = 0; a < 4; ++a)
        #pragma unroll
        for (int b = 0; b < 4; ++b)
            acc[a][b] = (f32x4){0.f, 0.f, 0.f, 0.f};

    const char* AsB = (const char*)As;
    const char* BsB = (const char*)Bs;

    for (int step = 0; step < KSTEPS; ++step) {
        const int t  = step >> 1;
        const int c0 = (step & 1) * 64;
        const int tapoff = (t / 3) * (W * CIN) + (t % 3) * CIN + c0;
        const int kb = step * BK;
        #pragma unroll
        for (int i = 0; i < 4; ++i)
            __builtin_amdgcn_global_load_lds(
                (AS_G unsigned int*)(xt + aBase[i] + tapoff + csel),
                (AS_L unsigned int*)((char*)As + (wv * 4 + i) * 1024),
                16, 0, 0);
        #pragma unroll
        for (int i = 0; i < 4; ++i)
            __builtin_amdgcn_global_load_lds(
                (AS_G unsigned int*)(bp + bBase[i] + kb + csel),
                (AS_L unsigned int*)((char*)Bs + (wv * 4 + i) * 1024),
                16, 0, 0);
        __syncthreads();   // compiler drains vmcnt before barrier
        #pragma unroll
        for (int ks = 0; ks < 2; ++ks) {
            bf16x8 af[4], bfr[4];
            #pragma unroll
            for (int mi = 0; mi < 4; ++mi)
                af[mi] = *(const bf16x8*)(AsB + aRow + mi * 2048 + colx[ks]);
            #pragma unroll
            for (int ni = 0; ni < 4; ++ni)
                bfr[ni] = *(const bf16x8*)(BsB + bRow + ni * 2048 + colx[ks]);
            #pragma unroll
            for (int mi = 0; mi < 4; ++mi)
                #pragma unroll
                for (int ni = 0; ni < 4; ++ni)
                    acc[mi][ni] = __builtin_amdgcn_mfma_f32_16x16x32_bf16(
                        bfr[ni], af[mi], acc[mi][ni], 0, 0, 0);   // D rows=o, cols=m
        }
        __syncthreads();
    }

    // epilogue: D col = lane&15 = m (consecutive!), row = (lane>>4)*4+j = o
    f32x4 bv[4];
    #pragma unroll
    for (int ni = 0; ni < 4; ++ni)
        bv[ni] = *(const f32x4*)(bias + wc * 64 + ni * 16 + lq * 4);
    #pragma unroll
    for (int mi = 0; mi < 4; ++mi) {
        int m = m0 + wr * 64 + mi * 16 + lr;
        if (m < M_TOT) {
            int n  = m / PIX;
            int r  = m - n * PIX;
            int y  = r / WO;
            int xx = r - y * WO;
            float* ob = out + (size_t)n * OCH * PIX + y * WO + xx;
            #pragma unroll
            for (int ni = 0; ni < 4; ++ni)
                #pragma unroll
                for (int j = 0; j < 4; ++j) {
                    int o = wc * 64 + ni * 16 + lq * 4 + j;
                    ob[(size_t)o * PIX] = acc[mi][ni][j] + bv[ni][j];
                }
        }
    }
}

extern "C" void kernel_launch(void* const* d_in, const int* in_sizes, int n_in,
                              void* d_out, int out_size, void* d_ws, size_t ws_size,
                              hipStream_t stream) {
    const float* x    = (const float*)d_in[0];
    const float* wsrc = (const float*)d_in[1];
    const float* bias = (const float*)d_in[2];
    float* out = (float*)d_out;
    unsigned short* xt = (unsigned short*)d_ws;                 // 16 MiB NHWC bf16
    unsigned short* bp = xt + (size_t)NIMG * H * W * CIN;       // 288 KiB weights
    prep_kernel<<<dim3(NIMG * H + (OCH * K_TOT + 255) / 256), dim3(256), 0, stream>>>(
        x, wsrc, xt, bp);
    gemm_kernel<<<dim3(NWG), dim3(256), 0, stream>>>(xt, bp, bias, out);
}